// Round 5
// baseline (1536.004 us; speedup 1.0000x reference)
//
#include <hip/hip_runtime.h>

#define NVV 4096
#define NCC 16384

typedef __attribute__((ext_vector_type(8))) short short8;
typedef __attribute__((ext_vector_type(4))) short short4v;
typedef __attribute__((ext_vector_type(4))) float f32x4;

__device__ __forceinline__ short f2bf(float f) {
  union { float f; unsigned u; } v; v.f = f;
  unsigned r = v.u + 0x7fffu + ((v.u >> 16) & 1u);
  return (short)(r >> 16);
}

template<typename AT>
__device__ __forceinline__ short8 load8v(const AT* p) {
  if constexpr (sizeof(AT) == 2) {
    return *(const short8*)p;
  } else {
    const f32x4* q = (const f32x4*)p;
    f32x4 a = q[0], b = q[1];
    short8 o;
#pragma unroll
    for (int j = 0; j < 4; ++j) { o[j] = f2bf(a[j]); o[j + 4] = f2bf(b[j]); }
    return o;
  }
}

// ---------------- fp32 -> bf16 bulk conversion (fallback tier) ----------------
__global__ __launch_bounds__(256) void k_conv(const float* __restrict__ src,
                                              short* __restrict__ dst, int n8) {
  int i = blockIdx.x * blockDim.x + threadIdx.x;
  const int stride = gridDim.x * blockDim.x;
  for (; i < n8; i += stride) {
    const f32x4* q = (const f32x4*)(src + (size_t)i * 8);
    f32x4 a = q[0], b = q[1];
    short8 o;
#pragma unroll
    for (int j = 0; j < 4; ++j) { o[j] = f2bf(a[j]); o[j + 4] = f2bf(b[j]); }
    *(short8*)(dst + (size_t)i * 8) = o;
  }
}

// ---------------- fused fp32 -> bf16 convert + transpose ----------------
// 64x64 tiles, 16 elems/thread, short8 stores both sides.
__global__ __launch_bounds__(256) void k_convT(const float* __restrict__ src,
                                               short* __restrict__ dstN,
                                               short* __restrict__ dstT,
                                               int R, int C) {
  __shared__ short t[64][66];
  const int r0 = blockIdx.y * 64, c0 = blockIdx.x * 64;
  const int tr = threadIdx.x >> 2;          // 0..63
  const int q  = (threadIdx.x & 3) << 4;    // 0,16,32,48
  const float* s = src + (size_t)(r0 + tr) * C + c0 + q;
  const f32x4 v0 = *(const f32x4*)(s);
  const f32x4 v1 = *(const f32x4*)(s + 4);
  const f32x4 v2 = *(const f32x4*)(s + 8);
  const f32x4 v3 = *(const f32x4*)(s + 12);
  short8 a, b;
#pragma unroll
  for (int j = 0; j < 4; ++j) {
    a[j] = f2bf(v0[j]); a[4 + j] = f2bf(v1[j]);
    b[j] = f2bf(v2[j]); b[4 + j] = f2bf(v3[j]);
  }
  short* dn = dstN + (size_t)(r0 + tr) * C + c0 + q;
  *(short8*)dn = a;
  *(short8*)(dn + 8) = b;
#pragma unroll
  for (int j = 0; j < 8; ++j) { t[tr][q + j] = a[j]; t[tr][q + 8 + j] = b[j]; }
  __syncthreads();
  short8 oa, ob;
#pragma unroll
  for (int j = 0; j < 8; ++j) { oa[j] = t[q + j][tr]; ob[j] = t[q + 8 + j][tr]; }
  short* dt = dstT + (size_t)(c0 + tr) * R + r0 + q;
  *(short8*)dt = oa;
  *(short8*)(dt + 8) = ob;
}

// ---------------- small MLP (writes TRANSPOSED bf16) ----------------
// SRC=0: labels only. SRC=1: embs f32 [Nrows][128].
// SRC=2: embs = f32 partials [KS][NCC][128]; x = relu(sum + bias).
template<int SRC, int NROW>
__global__ __launch_bounds__(128) void k_mlp(
    const float* __restrict__ labels, const float* __restrict__ embs,
    const float* __restrict__ bias,
    const float* __restrict__ Wp, const float* __restrict__ Wn,
    short* __restrict__ Tp, short* __restrict__ Tn, int Nrows, int KS) {
  __shared__ float xs[NROW][130];
  const int n = threadIdx.x;
  const int m0 = blockIdx.x * NROW;
  if (SRC == 2) {
#pragma unroll
    for (int r = 0; r < NROW; ++r) {
      const size_t m = m0 + r;
      float v = bias[n];
      for (int ks = 0; ks < KS; ++ks)
        v += embs[((size_t)ks * NCC + m) * 128 + n];
      xs[r][n] = fmaxf(v, 0.f);
    }
    __syncthreads();
  }
  float ap[NROW] = {}, an[NROW] = {};
  const int JMAX = (SRC == 0) ? 8 : 136;
  for (int j = 0; j < JMAX; ++j) {
    const float wp = Wp[j * 128 + n], wn = Wn[j * 128 + n];
#pragma unroll
    for (int r = 0; r < NROW; ++r) {
      float x;
      if (j < 8)            x = labels[(size_t)(m0 + r) * 8 + j];
      else if (SRC == 2)    x = xs[r][j - 8];
      else                  x = embs[(size_t)(m0 + r) * 128 + (j - 8)];
      ap[r] = fmaf(x, wp, ap[r]);
      an[r] = fmaf(x, wn, an[r]);
    }
  }
  short8 vp0, vn0, vp1, vn1;
#pragma unroll
  for (int r = 0; r < 8; ++r) {
    vp0[r] = f2bf(ap[r]); vn0[r] = f2bf(an[r]);
    vp1[r] = f2bf(ap[8 + r]); vn1[r] = f2bf(an[8 + r]);
  }
  *(short8*)(Tp + (size_t)n * Nrows + m0) = vp0;
  *(short8*)(Tp + (size_t)n * Nrows + m0 + 8) = vp1;
  *(short8*)(Tn + (size_t)n * Nrows + m0) = vn0;
  *(short8*)(Tn + (size_t)n * Nrows + m0 + 8) = vn1;
}

// ---------------- m97-style GEMM: BM=64, BN=128, BK=64, 3 blk/CU ----------------
// partial[z][m][n] = sum_{k in split z} Ap[m][k]*Bp[n][k] + An[m][k]*Bn[n][k]
// A bf16 [M][lda] row-major; B bf16 [128][ldb] n-major (k-contiguous).
// 256 threads = 2x2 waves, wave tile 32x64, acc[2][4] f32x4. LDS 48 KB.
__global__ __launch_bounds__(256, 3) void k_gemm5(
    const short* __restrict__ Ap, const short* __restrict__ An,
    const short* __restrict__ Bp, const short* __restrict__ Bn,
    float* __restrict__ C, int M, int lda, int ldb, int Klen) {
  __shared__ __align__(16) short sA[2][4096];
  __shared__ __align__(16) short sB[2][8192];
  const int tid = threadIdx.x;
  const int w = tid >> 6, l = tid & 63, lr = l & 15, lh = l >> 4;
  const int wr = w >> 1, wc = w & 1;
  const int m0 = blockIdx.x * 64;
  const int Koff = (int)blockIdx.z * Klen;
  const int T = Klen >> 6;

  // staging: chunk c = i*256 + tid covers row c>>3, 8 swizzled shorts
  const int srow = tid >> 3;                       // 0..31
  const int scol = ((tid & 7) ^ (srow & 7)) << 3;  // pre-swizzled source col
  const short* gA0 = Ap + (size_t)(m0 + srow) * lda + Koff + scol;
  const short* gA1 = An + (size_t)(m0 + srow) * lda + Koff + scol;
  const short* gB0 = Bp + (size_t)srow * ldb + Koff + scol;
  const short* gB1 = Bn + (size_t)srow * ldb + Koff + scol;

  f32x4 acc[2][4] = {};

  for (int step = 0; step < T; ++step) {
    const int k0 = step << 6;
#pragma unroll
    for (int i = 0; i < 2; ++i) {
      const size_t ra = (size_t)(i * 32) * lda + k0;
      const int ld = i * 2048 + w * 512;
      __builtin_amdgcn_global_load_lds(
          (const __attribute__((address_space(1))) void*)(gA0 + ra),
          (__attribute__((address_space(3))) void*)(&sA[0][ld]), 16, 0, 0);
      __builtin_amdgcn_global_load_lds(
          (const __attribute__((address_space(1))) void*)(gA1 + ra),
          (__attribute__((address_space(3))) void*)(&sA[1][ld]), 16, 0, 0);
    }
#pragma unroll
    for (int i = 0; i < 4; ++i) {
      const size_t rb = (size_t)(i * 32) * ldb + k0;
      const int ld = i * 2048 + w * 512;
      __builtin_amdgcn_global_load_lds(
          (const __attribute__((address_space(1))) void*)(gB0 + rb),
          (__attribute__((address_space(3))) void*)(&sB[0][ld]), 16, 0, 0);
      __builtin_amdgcn_global_load_lds(
          (const __attribute__((address_space(1))) void*)(gB1 + rb),
          (__attribute__((address_space(3))) void*)(&sB[1][ld]), 16, 0, 0);
    }
    __syncthreads();
#pragma unroll
    for (int kk = 0; kk < 2; ++kk) {
#pragma unroll
      for (int mat = 0; mat < 2; ++mat) {
        const int kc = (kk << 2) + lh;
        short8 a[2], b[4];
#pragma unroll
        for (int mi = 0; mi < 2; ++mi) {
          const int row = (wr << 5) + (mi << 4) + lr;
          a[mi] = *(const short8*)&sA[mat][(row << 6) + ((kc ^ (row & 7)) << 3)];
        }
#pragma unroll
        for (int nj = 0; nj < 4; ++nj) {
          const int n = (wc << 6) + (nj << 4) + lr;
          b[nj] = *(const short8*)&sB[mat][(n << 6) + ((kc ^ (n & 7)) << 3)];
        }
#pragma unroll
        for (int mi = 0; mi < 2; ++mi)
#pragma unroll
          for (int nj = 0; nj < 4; ++nj)
            acc[mi][nj] = __builtin_amdgcn_mfma_f32_16x16x32_bf16(
                a[mi], b[nj], acc[mi][nj], 0, 0, 0);
      }
    }
    __syncthreads();
  }

  const size_t crow0 = (size_t)blockIdx.z * M + m0 + (wr << 5) + (lh << 2);
#pragma unroll
  for (int mi = 0; mi < 2; ++mi)
#pragma unroll
    for (int nj = 0; nj < 4; ++nj) {
      const int col = (wc << 6) + (nj << 4) + lr;
#pragma unroll
      for (int r = 0; r < 4; ++r)
        C[(crow0 + (mi << 4) + r) * 128 + col] = acc[mi][nj][r];
    }
}

// ---------------- legacy GEMM (fallback tiers) ----------------
template<typename AT, bool TRANSA, int EPI>
__global__ __launch_bounds__(256) void k_gemm(
    const AT* __restrict__ Ap, const AT* __restrict__ An,
    const short* __restrict__ Bp, const short* __restrict__ Bn,
    const float* __restrict__ bias, float* __restrict__ C,
    int M, int lda, int ldb, int Klen) {
  __shared__ __align__(16) short sA[2][32 * 64];
  __shared__ __align__(16) short sB[2][64 * 64];
  const int tid = threadIdx.x;
  const int w = tid >> 6, l = tid & 63, lr = l & 15, lh = l >> 4;
  const int m0 = blockIdx.x * 32, n0 = blockIdx.y * 64;
  const int Koff = blockIdx.z * Klen;
  f32x4 acc0 = {0.f, 0.f, 0.f, 0.f}, acc1 = {0.f, 0.f, 0.f, 0.f};

  for (int step = 0; step < (Klen >> 6); ++step) {
    const int k0 = Koff + (step << 6);
    __syncthreads();
    if (!TRANSA) {
      const int m = tid >> 3, kc = tid & 7;
      const size_t ga = (size_t)(m0 + m) * lda + k0 + (kc << 3);
      const int ad = (m << 6) + ((kc ^ (m & 7)) << 3);
      *(short8*)&sA[0][ad] = load8v(Ap + ga);
      *(short8*)&sA[1][ad] = load8v(An + ga);
    } else {
      const int r = tid >> 2, c8 = (tid & 3) << 3;
      const size_t ga = (size_t)(k0 + r) * lda + m0 + c8;
      short8 vp = load8v(Ap + ga), vn = load8v(An + ga);
#pragma unroll
      for (int j = 0; j < 8; ++j) {
        const int m = c8 + j;
        const int ad = (m << 6) + ((((r >> 3)) ^ (m & 7)) << 3) + (r & 7);
        sA[0][ad] = vp[j];
        sA[1][ad] = vn[j];
      }
    }
#pragma unroll
    for (int i = 0; i < 2; ++i) {
      const int c = (i << 8) + tid;
      const int n = c >> 3, kc = c & 7;
      const size_t gb = (size_t)(n0 + n) * ldb + k0 + (kc << 3);
      const int ad = (n << 6) + ((kc ^ (n & 7)) << 3);
      *(short8*)&sB[0][ad] = *(const short8*)(Bp + gb);
      *(short8*)&sB[1][ad] = *(const short8*)(Bn + gb);
    }
    __syncthreads();
#pragma unroll
    for (int kh = 0; kh < 2; ++kh) {
      const int kc = (kh << 2) + lh;
      const int bn_ = (w << 4) + lr;
      short8 bp = *(short8*)&sB[0][(bn_ << 6) + ((kc ^ (bn_ & 7)) << 3)];
      short8 bnv = *(short8*)&sB[1][(bn_ << 6) + ((kc ^ (bn_ & 7)) << 3)];
      short8 a0p = *(short8*)&sA[0][(lr << 6) + ((kc ^ (lr & 7)) << 3)];
      short8 a0n = *(short8*)&sA[1][(lr << 6) + ((kc ^ (lr & 7)) << 3)];
      const int m1 = 16 + lr;
      short8 a1p = *(short8*)&sA[0][(m1 << 6) + ((kc ^ (m1 & 7)) << 3)];
      short8 a1n = *(short8*)&sA[1][(m1 << 6) + ((kc ^ (m1 & 7)) << 3)];
      acc0 = __builtin_amdgcn_mfma_f32_16x16x32_bf16(a0p, bp, acc0, 0, 0, 0);
      acc0 = __builtin_amdgcn_mfma_f32_16x16x32_bf16(a0n, bnv, acc0, 0, 0, 0);
      acc1 = __builtin_amdgcn_mfma_f32_16x16x32_bf16(a1p, bp, acc1, 0, 0, 0);
      acc1 = __builtin_amdgcn_mfma_f32_16x16x32_bf16(a1n, bnv, acc1, 0, 0, 0);
    }
  }
  const int n = n0 + (w << 4) + lr;
#pragma unroll
  for (int mf = 0; mf < 2; ++mf) {
    f32x4 a = mf ? acc1 : acc0;
#pragma unroll
    for (int r = 0; r < 4; ++r) {
      const int m = m0 + (mf << 4) + (lh << 2) + r;
      float c = a[r];
      if (EPI == 0) {
        c += bias[n];
        c = fmaxf(c, 0.f);
        C[(size_t)m * 128 + n] = c;
      } else {
        C[((size_t)blockIdx.z * M + m) * 128 + n] = c;
      }
    }
  }
}

// ---------------- splitK reduce + bias + relu + LayerNorm ----------------
template<int KS>
__global__ __launch_bounds__(256) void k_reduce_ln(
    const float* __restrict__ part, const float* __restrict__ bias,
    const float* __restrict__ gamma, const float* __restrict__ beta,
    float* __restrict__ out) {
  const int w = threadIdx.x >> 6, l = threadIdx.x & 63;
  const int m = blockIdx.x * 4 + w;
  const int n0 = l << 1;
  float x0 = bias[n0], x1 = bias[n0 + 1];
#pragma unroll
  for (int ks = 0; ks < KS; ++ks) {
    const size_t o = ((size_t)ks * NVV + m) * 128 + n0;
    x0 += part[o];
    x1 += part[o + 1];
  }
  x0 = fmaxf(x0, 0.f);
  x1 = fmaxf(x1, 0.f);
  float s = x0 + x1, q = x0 * x0 + x1 * x1;
#pragma unroll
  for (int off = 32; off; off >>= 1) {
    s += __shfl_xor(s, off);
    q += __shfl_xor(q, off);
  }
  const float mu = s * (1.f / 128.f);
  const float var = q * (1.f / 128.f) - mu * mu;
  const float inv = 1.f / sqrtf(var + 1e-5f);
  out[(size_t)m * 128 + n0]     = (x0 - mu) * inv * gamma[n0] + beta[n0];
  out[(size_t)m * 128 + n0 + 1] = (x1 - mu) * inv * gamma[n0 + 1] + beta[n0 + 1];
}

extern "C" void kernel_launch(void* const* d_in, const int* in_sizes, int n_in,
                              void* d_out, int out_size, void* d_ws, size_t ws_size,
                              hipStream_t stream) {
  const float* vlabels  = (const float*)d_in[0];
  const float* clabels  = (const float*)d_in[1];
  const float* cmat_pos = (const float*)d_in[2];
  const float* cmat_neg = (const float*)d_in[3];
  const float* Wvp = (const float*)d_in[4];
  const float* Wvn = (const float*)d_in[5];
  const float* Bv  = (const float*)d_in[6];
  const float* Wcp = (const float*)d_in[7];
  const float* Wcn = (const float*)d_in[8];
  const float* Bc  = (const float*)d_in[9];
  const float* gam = (const float*)d_in[10];
  const float* bet = (const float*)d_in[11];
  float* out = (float*)d_out;

  char* base = (char*)d_ws;
  const size_t SZ_vT  = (size_t)128 * NVV * 2;     // 1 MB
  const size_t SZ_cT  = (size_t)128 * NCC * 2;     // 4 MB
  const size_t SZ_cm  = (size_t)NCC * NVV * 2;     // 128 MB
  const size_t SZ_p8  = (size_t)NCC * 128 * 4;     // 8 MB (one NCC partial)

  // ---- fast layout: pvT nvT pcT ncT cmPb cmNb cmTP cmTN part ----
  size_t o = 0;
  auto al = [&](size_t b) { size_t p = o; o += (b + 255) & ~(size_t)255; return p; };
  short* pvT  = (short*)(base + al(SZ_vT));
  short* nvT  = (short*)(base + al(SZ_vT));
  short* pcT  = (short*)(base + al(SZ_cT));
  short* ncT  = (short*)(base + al(SZ_cT));
  short* cmPb = (short*)(base + al(SZ_cm));
  short* cmNb = (short*)(base + al(SZ_cm));
  short* cmTP = (short*)(base + al(SZ_cm));
  short* cmTN = (short*)(base + al(SZ_cm));
  float* part = (float*)(base + al(4 * SZ_p8));
  const size_t needFA = o;                         // SK 4/16, part 32MB
  const size_t needFB = needFA - 2 * SZ_p8;        // SK 2/8,  part 16MB

  const bool fastA = ws_size >= needFA;
  const bool fastB = !fastA && ws_size >= needFB;

  if (fastA || fastB) {
    const int SK1 = fastA ? 4 : 2;
    const int SK2 = fastA ? 16 : 8;
    k_convT<<<dim3(NVV / 64, NCC / 64), 256, 0, stream>>>(cmat_pos, cmPb, cmTP, NCC, NVV);
    k_convT<<<dim3(NVV / 64, NCC / 64), 256, 0, stream>>>(cmat_neg, cmNb, cmTN, NCC, NVV);

    for (int it = 0; it < 4; ++it) {
      if (it == 0)
        k_mlp<0, 16><<<NVV / 16, 128, 0, stream>>>(vlabels, nullptr, nullptr, Wvp, Wvn, pvT, nvT, NVV, 0);
      else
        k_mlp<1, 16><<<NVV / 16, 128, 0, stream>>>(vlabels, out, nullptr, Wvp, Wvn, pvT, nvT, NVV, 0);

      // GEMM1: partials[SK1][NCC][128] = cmat @ pv (+neg)
      k_gemm5<<<dim3(NCC / 64, 1, SK1), 256, 0, stream>>>(
          cmPb, cmNb, pvT, nvT, part, NCC, NVV, NVV, NVV / SK1);
      // clause MLP fused with GEMM1 partial reduce
      k_mlp<2, 16><<<NCC / 16, 128, 0, stream>>>(clabels, part, Bv, Wcp, Wcn, pcT, ncT, NCC, SK1);

      // GEMM2: partials[SK2][NVV][128] = cmat^T @ pc (+neg)
      k_gemm5<<<dim3(NVV / 64, 1, SK2), 256, 0, stream>>>(
          cmTP, cmTN, pcT, ncT, part, NVV, NCC, NCC, NCC / SK2);
      if (fastA)
        k_reduce_ln<16><<<NVV / 4, 256, 0, stream>>>(part, Bc, gam, bet, out);
      else
        k_reduce_ln<8><<<NVV / 4, 256, 0, stream>>>(part, Bc, gam, bet, out);
    }
    return;
  }

  // ---- legacy layout: pvT nvT pcT ncT part(16MB) cemb(8MB) cmPb cmNb ----
  o = 0;
  pvT  = (short*)(base + al(SZ_vT));
  nvT  = (short*)(base + al(SZ_vT));
  pcT  = (short*)(base + al(SZ_cT));
  ncT  = (short*)(base + al(SZ_cT));
  part = (float*)(base + al(2 * SZ_p8));
  float* cemb = (float*)(base + al(SZ_p8));
  cmPb = (short*)(base + al(SZ_cm));
  cmNb = (short*)(base + al(SZ_cm));
  const size_t needN = o;
  const bool big = ws_size >= needN;

  if (big) {
    k_conv<<<4096, 256, 0, stream>>>(cmat_pos, cmPb, NCC * NVV / 8);
    k_conv<<<4096, 256, 0, stream>>>(cmat_neg, cmNb, NCC * NVV / 8);
  }

  for (int it = 0; it < 4; ++it) {
    if (it == 0)
      k_mlp<0, 16><<<NVV / 16, 128, 0, stream>>>(vlabels, nullptr, nullptr, Wvp, Wvn, pvT, nvT, NVV, 0);
    else
      k_mlp<1, 16><<<NVV / 16, 128, 0, stream>>>(vlabels, out, nullptr, Wvp, Wvn, pvT, nvT, NVV, 0);

    if (big) {
      k_gemm5<<<dim3(NCC / 64, 1, 2), 256, 0, stream>>>(
          cmPb, cmNb, pvT, nvT, part, NCC, NVV, NVV, NVV / 2);
      k_mlp<2, 16><<<NCC / 16, 128, 0, stream>>>(clabels, part, Bv, Wcp, Wcn, pcT, ncT, NCC, 2);
      k_gemm<short, true, 1><<<dim3(NVV / 32, 2, 4), 256, 0, stream>>>(
          cmPb, cmNb, pcT, ncT, nullptr, part, NVV, NVV, NCC, NVV);
      k_reduce_ln<4><<<NVV / 4, 256, 0, stream>>>(part, Bc, gam, bet, out);
    } else {
      k_gemm<float, false, 0><<<dim3(NCC / 32, 2, 1), 256, 0, stream>>>(
          cmat_pos, cmat_neg, pvT, nvT, Bv, cemb, NCC, NVV, NVV, NVV);
      k_mlp<1, 16><<<NCC / 16, 128, 0, stream>>>(clabels, cemb, nullptr, Wcp, Wcn, pcT, ncT, NCC, 0);
      k_gemm<float, true, 1><<<dim3(NVV / 32, 2, 4), 256, 0, stream>>>(
          cmat_pos, cmat_neg, pcT, ncT, nullptr, part, NVV, NVV, NCC, NVV);
      k_reduce_ln<4><<<NVV / 4, 256, 0, stream>>>(part, Bc, gam, bet, out);
    }
  }
}

// Round 6
// 1381.516 us; speedup vs baseline: 1.1118x; 1.1118x over previous
//
#include <hip/hip_runtime.h>

#define NVV 4096
#define NCC 16384
#define AS1 __attribute__((address_space(1)))
#define AS3 __attribute__((address_space(3)))

typedef __attribute__((ext_vector_type(8))) short short8;
typedef __attribute__((ext_vector_type(4))) short short4v;
typedef __attribute__((ext_vector_type(4))) float f32x4;

__device__ __forceinline__ short f2bf(float f) {
  union { float f; unsigned u; } v; v.f = f;
  unsigned r = v.u + 0x7fffu + ((v.u >> 16) & 1u);
  return (short)(r >> 16);
}

template<typename AT>
__device__ __forceinline__ short8 load8v(const AT* p) {
  if constexpr (sizeof(AT) == 2) {
    return *(const short8*)p;
  } else {
    const f32x4* q = (const f32x4*)p;
    f32x4 a = q[0], b = q[1];
    short8 o;
#pragma unroll
    for (int j = 0; j < 4; ++j) { o[j] = f2bf(a[j]); o[j + 4] = f2bf(b[j]); }
    return o;
  }
}

// ---------------- fp32 -> bf16 bulk conversion (fallback tier) ----------------
__global__ __launch_bounds__(256) void k_conv(const float* __restrict__ src,
                                              short* __restrict__ dst, int n8) {
  int i = blockIdx.x * blockDim.x + threadIdx.x;
  const int stride = gridDim.x * blockDim.x;
  for (; i < n8; i += stride) {
    const f32x4* q = (const f32x4*)(src + (size_t)i * 8);
    f32x4 a = q[0], b = q[1];
    short8 o;
#pragma unroll
    for (int j = 0; j < 4; ++j) { o[j] = f2bf(a[j]); o[j + 4] = f2bf(b[j]); }
    *(short8*)(dst + (size_t)i * 8) = o;
  }
}

// ---------------- fused fp32 -> bf16 convert + transpose (64x64 tiles) ----------------
__global__ __launch_bounds__(256) void k_convT(const float* __restrict__ src,
                                               short* __restrict__ dstN,
                                               short* __restrict__ dstT,
                                               int R, int C) {
  __shared__ short t[64][66];
  const int r0 = blockIdx.y * 64, c0 = blockIdx.x * 64;
  const int tr = threadIdx.x >> 2;          // 0..63
  const int q  = (threadIdx.x & 3) << 4;    // 0,16,32,48
  const float* s = src + (size_t)(r0 + tr) * C + c0 + q;
  const f32x4 v0 = *(const f32x4*)(s);
  const f32x4 v1 = *(const f32x4*)(s + 4);
  const f32x4 v2 = *(const f32x4*)(s + 8);
  const f32x4 v3 = *(const f32x4*)(s + 12);
  short8 a, b;
#pragma unroll
  for (int j = 0; j < 4; ++j) {
    a[j] = f2bf(v0[j]); a[4 + j] = f2bf(v1[j]);
    b[j] = f2bf(v2[j]); b[4 + j] = f2bf(v3[j]);
  }
  short* dn = dstN + (size_t)(r0 + tr) * C + c0 + q;
  *(short8*)dn = a;
  *(short8*)(dn + 8) = b;
#pragma unroll
  for (int j = 0; j < 8; ++j) { t[tr][q + j] = a[j]; t[tr][q + 8 + j] = b[j]; }
  __syncthreads();
  short8 oa, ob;
#pragma unroll
  for (int j = 0; j < 8; ++j) { oa[j] = t[q + j][tr]; ob[j] = t[q + 8 + j][tr]; }
  short* dt = dstT + (size_t)(c0 + tr) * R + r0 + q;
  *(short8*)dt = oa;
  *(short8*)(dt + 8) = ob;
}

// ---------------- small MLP (writes TRANSPOSED bf16) ----------------
// SRC=0: labels only. SRC=1: embs f32 [Nrows][128].
// SRC=2: embs = f32 partials [KS][NCC][128]; x = relu(sum + bias).
template<int SRC, int NROW>
__global__ __launch_bounds__(128) void k_mlp(
    const float* __restrict__ labels, const float* __restrict__ embs,
    const float* __restrict__ bias,
    const float* __restrict__ Wp, const float* __restrict__ Wn,
    short* __restrict__ Tp, short* __restrict__ Tn, int Nrows, int KS) {
  __shared__ float xs[NROW][130];
  const int n = threadIdx.x;
  const int m0 = blockIdx.x * NROW;
  if (SRC == 2) {
#pragma unroll
    for (int r = 0; r < NROW; ++r) {
      const size_t m = m0 + r;
      float v = bias[n];
      for (int ks = 0; ks < KS; ++ks)
        v += embs[((size_t)ks * NCC + m) * 128 + n];
      xs[r][n] = fmaxf(v, 0.f);
    }
    __syncthreads();
  }
  float ap[NROW] = {}, an[NROW] = {};
  const int JMAX = (SRC == 0) ? 8 : 136;
  for (int j = 0; j < JMAX; ++j) {
    const float wp = Wp[j * 128 + n], wn = Wn[j * 128 + n];
#pragma unroll
    for (int r = 0; r < NROW; ++r) {
      float x;
      if (j < 8)            x = labels[(size_t)(m0 + r) * 8 + j];
      else if (SRC == 2)    x = xs[r][j - 8];
      else                  x = embs[(size_t)(m0 + r) * 128 + (j - 8)];
      ap[r] = fmaf(x, wp, ap[r]);
      an[r] = fmaf(x, wn, an[r]);
    }
  }
  short8 vp0, vn0, vp1, vn1;
#pragma unroll
  for (int r = 0; r < 8; ++r) {
    vp0[r] = f2bf(ap[r]); vn0[r] = f2bf(an[r]);
    vp1[r] = f2bf(ap[8 + r]); vn1[r] = f2bf(an[8 + r]);
  }
  *(short8*)(Tp + (size_t)n * Nrows + m0) = vp0;
  *(short8*)(Tp + (size_t)n * Nrows + m0 + 8) = vp1;
  *(short8*)(Tn + (size_t)n * Nrows + m0) = vn0;
  *(short8*)(Tn + (size_t)n * Nrows + m0 + 8) = vn1;
}

// ---------------- pipelined streaming GEMM (T4: counted vmcnt) ----------------
// C[m][n] = sum_k Ap[m][k]*Bp[n][k] + An[m][k]*Bn[n][k]   (N = 128 fixed)
// A bf16 [M][lda] row-major; B bf16 [128][ldb] n-major (k-contiguous).
// BM=64, BN=128, BK=64; pos/neg alternate as pipeline tiles (T = 2*Klen/64).
// 4 LDS bufs x 24KB (A 8KB + B 16KB), stage 2 tiles ahead via global_load_lds
// (XOR swizzle pre-applied to GLOBAL source col; LDS dest linear).
// ONE barrier + s_waitcnt vmcnt(12) per step (6 loads/step/wave; never 0).
// Hazards: buf[t&3] re-staged at iter t+2; iter t+1's barrier separates its
// last read (iter t) from that overwrite. Tail stages dummy tiles 0/1 to keep
// the vmcnt schedule uniform.
// EPI=0: C = relu(acc + bias) f32 [M][128].  EPI=1: partial at C[zw*M + ...].
// LSK: log2(splitK); zw = blockIdx.x & (SK-1) so each XCD sees few K-quarters.
template<int EPI, int LSK>
__global__ __launch_bounds__(256, 1) void k_gemm6(
    const short* __restrict__ Ap, const short* __restrict__ An,
    const short* __restrict__ Bp, const short* __restrict__ Bn,
    const float* __restrict__ bias, float* __restrict__ C,
    int M, int lda, int ldb, int Klen) {
  __shared__ __align__(16) short sb[4][12288];  // 96 KB
  const int tid = threadIdx.x;
  const int w = tid >> 6, l = tid & 63, lr = l & 15, lh = l >> 4;
  const int wr = w >> 1, wc = w & 1;
  const int id = blockIdx.x;
  const int zw = id & ((1 << LSK) - 1);
  const int xw = id >> LSK;
  const int m0 = xw * 64;
  const int Koff = zw * Klen;
  const int T = (Klen >> 6) << 1;

  // staging source addresses (swizzle applied to global column)
  const int srow = tid >> 3;                       // 0..31
  const int scol = ((tid & 7) ^ (srow & 7)) << 3;  // pre-swizzled col (shorts)
  const short* gAp = Ap + (size_t)(m0 + srow) * lda + Koff + scol;
  const short* gAn = An + (size_t)(m0 + srow) * lda + Koff + scol;
  const short* gBp = Bp + (size_t)srow * ldb + Koff + scol;
  const short* gBn = Bn + (size_t)srow * ldb + Koff + scol;

  f32x4 acc[2][4] = {};

  auto stage = [&](int t, int buf) {
    const int tt = (t < T) ? t : t - T;            // tail: dummy re-stage
    const int k0 = (tt >> 1) << 6;
    const short* A = (tt & 1) ? gAn : gAp;
    const short* B = (tt & 1) ? gBn : gBp;
#pragma unroll
    for (int i = 0; i < 2; ++i)                    // A: 64 rows
      __builtin_amdgcn_global_load_lds(
          (const AS1 void*)(A + (size_t)(i * 32) * lda + k0),
          (AS3 void*)(&sb[buf][i * 2048 + w * 512]), 16, 0, 0);
#pragma unroll
    for (int i = 0; i < 4; ++i)                    // B: 128 rows
      __builtin_amdgcn_global_load_lds(
          (const AS1 void*)(B + (size_t)(i * 32) * ldb + k0),
          (AS3 void*)(&sb[buf][4096 + i * 2048 + w * 512]), 16, 0, 0);
  };

  stage(0, 0);
  stage(1, 1);

  for (int t = 0; t < T; ++t) {
    stage(t + 2, (t + 2) & 3);
    // outstanding/wave: t(6) + t+1(6) + t+2(6) = 18 -> wait to 12 drains tile t
    asm volatile("s_waitcnt vmcnt(12)" ::: "memory");
    __builtin_amdgcn_s_barrier();
    asm volatile("" ::: "memory");
    const short* bp = &sb[t & 3][0];
#pragma unroll
    for (int kk = 0; kk < 2; ++kk) {
      const int kc = (kk << 2) + lh;
      short8 a[2], b[4];
#pragma unroll
      for (int mi = 0; mi < 2; ++mi) {
        const int row = (wr << 5) + (mi << 4) + lr;
        a[mi] = *(const short8*)&bp[(row << 6) + ((kc ^ (row & 7)) << 3)];
      }
#pragma unroll
      for (int nj = 0; nj < 4; ++nj) {
        const int n = (wc << 6) + (nj << 4) + lr;
        b[nj] = *(const short8*)&bp[4096 + (n << 6) + ((kc ^ (n & 7)) << 3)];
      }
#pragma unroll
      for (int mi = 0; mi < 2; ++mi)
#pragma unroll
        for (int nj = 0; nj < 4; ++nj)
          acc[mi][nj] = __builtin_amdgcn_mfma_f32_16x16x32_bf16(
              a[mi], b[nj], acc[mi][nj], 0, 0, 0);
    }
  }

#pragma unroll
  for (int mi = 0; mi < 2; ++mi)
#pragma unroll
    for (int nj = 0; nj < 4; ++nj) {
      const int col = (wc << 6) + (nj << 4) + lr;
#pragma unroll
      for (int r = 0; r < 4; ++r) {
        const int m = m0 + (wr << 5) + (mi << 4) + (lh << 2) + r;
        if (EPI == 0) {
          C[(size_t)m * 128 + col] = fmaxf(acc[mi][nj][r] + bias[col], 0.f);
        } else {
          C[((size_t)zw * M + m) * 128 + col] = acc[mi][nj][r];
        }
      }
    }
}

// ---------------- legacy GEMM (fallback tiers) ----------------
template<typename AT, bool TRANSA, int EPI>
__global__ __launch_bounds__(256) void k_gemm(
    const AT* __restrict__ Ap, const AT* __restrict__ An,
    const short* __restrict__ Bp, const short* __restrict__ Bn,
    const float* __restrict__ bias, float* __restrict__ C,
    int M, int lda, int ldb, int Klen) {
  __shared__ __align__(16) short sA[2][32 * 64];
  __shared__ __align__(16) short sB[2][64 * 64];
  const int tid = threadIdx.x;
  const int w = tid >> 6, l = tid & 63, lr = l & 15, lh = l >> 4;
  const int m0 = blockIdx.x * 32, n0 = blockIdx.y * 64;
  const int Koff = blockIdx.z * Klen;
  f32x4 acc0 = {0.f, 0.f, 0.f, 0.f}, acc1 = {0.f, 0.f, 0.f, 0.f};

  for (int step = 0; step < (Klen >> 6); ++step) {
    const int k0 = Koff + (step << 6);
    __syncthreads();
    if (!TRANSA) {
      const int m = tid >> 3, kc = tid & 7;
      const size_t ga = (size_t)(m0 + m) * lda + k0 + (kc << 3);
      const int ad = (m << 6) + ((kc ^ (m & 7)) << 3);
      *(short8*)&sA[0][ad] = load8v(Ap + ga);
      *(short8*)&sA[1][ad] = load8v(An + ga);
    } else {
      const int r = tid >> 2, c8 = (tid & 3) << 3;
      const size_t ga = (size_t)(k0 + r) * lda + m0 + c8;
      short8 vp = load8v(Ap + ga), vn = load8v(An + ga);
#pragma unroll
      for (int j = 0; j < 8; ++j) {
        const int m = c8 + j;
        const int ad = (m << 6) + ((((r >> 3)) ^ (m & 7)) << 3) + (r & 7);
        sA[0][ad] = vp[j];
        sA[1][ad] = vn[j];
      }
    }
#pragma unroll
    for (int i = 0; i < 2; ++i) {
      const int c = (i << 8) + tid;
      const int n = c >> 3, kc = c & 7;
      const size_t gb = (size_t)(n0 + n) * ldb + k0 + (kc << 3);
      const int ad = (n << 6) + ((kc ^ (n & 7)) << 3);
      *(short8*)&sB[0][ad] = *(const short8*)(Bp + gb);
      *(short8*)&sB[1][ad] = *(const short8*)(Bn + gb);
    }
    __syncthreads();
#pragma unroll
    for (int kh = 0; kh < 2; ++kh) {
      const int kc = (kh << 2) + lh;
      const int bn_ = (w << 4) + lr;
      short8 bpv = *(short8*)&sB[0][(bn_ << 6) + ((kc ^ (bn_ & 7)) << 3)];
      short8 bnv = *(short8*)&sB[1][(bn_ << 6) + ((kc ^ (bn_ & 7)) << 3)];
      short8 a0p = *(short8*)&sA[0][(lr << 6) + ((kc ^ (lr & 7)) << 3)];
      short8 a0n = *(short8*)&sA[1][(lr << 6) + ((kc ^ (lr & 7)) << 3)];
      const int m1 = 16 + lr;
      short8 a1p = *(short8*)&sA[0][(m1 << 6) + ((kc ^ (m1 & 7)) << 3)];
      short8 a1n = *(short8*)&sA[1][(m1 << 6) + ((kc ^ (m1 & 7)) << 3)];
      acc0 = __builtin_amdgcn_mfma_f32_16x16x32_bf16(a0p, bpv, acc0, 0, 0, 0);
      acc0 = __builtin_amdgcn_mfma_f32_16x16x32_bf16(a0n, bnv, acc0, 0, 0, 0);
      acc1 = __builtin_amdgcn_mfma_f32_16x16x32_bf16(a1p, bpv, acc1, 0, 0, 0);
      acc1 = __builtin_amdgcn_mfma_f32_16x16x32_bf16(a1n, bnv, acc1, 0, 0, 0);
    }
  }
  const int n = n0 + (w << 4) + lr;
#pragma unroll
  for (int mf = 0; mf < 2; ++mf) {
    f32x4 a = mf ? acc1 : acc0;
#pragma unroll
    for (int r = 0; r < 4; ++r) {
      const int m = m0 + (mf << 4) + (lh << 2) + r;
      float c = a[r];
      if (EPI == 0) {
        c += bias[n];
        c = fmaxf(c, 0.f);
        C[(size_t)m * 128 + n] = c;
      } else {
        C[((size_t)blockIdx.z * M + m) * 128 + n] = c;
      }
    }
  }
}

// ---------------- splitK reduce + bias + relu + LayerNorm ----------------
template<int KS>
__global__ __launch_bounds__(256) void k_reduce_ln(
    const float* __restrict__ part, const float* __restrict__ bias,
    const float* __restrict__ gamma, const float* __restrict__ beta,
    float* __restrict__ out) {
  const int w = threadIdx.x >> 6, l = threadIdx.x & 63;
  const int m = blockIdx.x * 4 + w;
  const int n0 = l << 1;
  float x0 = bias[n0], x1 = bias[n0 + 1];
#pragma unroll
  for (int ks = 0; ks < KS; ++ks) {
    const size_t o = ((size_t)ks * NVV + m) * 128 + n0;
    x0 += part[o];
    x1 += part[o + 1];
  }
  x0 = fmaxf(x0, 0.f);
  x1 = fmaxf(x1, 0.f);
  float s = x0 + x1, q = x0 * x0 + x1 * x1;
#pragma unroll
  for (int off = 32; off; off >>= 1) {
    s += __shfl_xor(s, off);
    q += __shfl_xor(q, off);
  }
  const float mu = s * (1.f / 128.f);
  const float var = q * (1.f / 128.f) - mu * mu;
  const float inv = 1.f / sqrtf(var + 1e-5f);
  out[(size_t)m * 128 + n0]     = (x0 - mu) * inv * gamma[n0] + beta[n0];
  out[(size_t)m * 128 + n0 + 1] = (x1 - mu) * inv * gamma[n0 + 1] + beta[n0 + 1];
}

extern "C" void kernel_launch(void* const* d_in, const int* in_sizes, int n_in,
                              void* d_out, int out_size, void* d_ws, size_t ws_size,
                              hipStream_t stream) {
  const float* vlabels  = (const float*)d_in[0];
  const float* clabels  = (const float*)d_in[1];
  const float* cmat_pos = (const float*)d_in[2];
  const float* cmat_neg = (const float*)d_in[3];
  const float* Wvp = (const float*)d_in[4];
  const float* Wvn = (const float*)d_in[5];
  const float* Bv  = (const float*)d_in[6];
  const float* Wcp = (const float*)d_in[7];
  const float* Wcn = (const float*)d_in[8];
  const float* Bc  = (const float*)d_in[9];
  const float* gam = (const float*)d_in[10];
  const float* bet = (const float*)d_in[11];
  float* out = (float*)d_out;

  char* base = (char*)d_ws;
  const size_t SZ_vT = (size_t)128 * NVV * 2;     // 1 MB
  const size_t SZ_cT = (size_t)128 * NCC * 2;     // 4 MB
  const size_t SZ_cm = (size_t)NCC * NVV * 2;     // 128 MB
  const size_t SZ_p8 = (size_t)NCC * 128 * 4;     // 8 MB

  size_t o = 0;
  auto al = [&](size_t b) { size_t p = o; o += (b + 255) & ~(size_t)255; return p; };

  // ---- fast layout: pvT nvT pcT ncT scratch8(cemb|part alias) cmPb cmNb cmTP cmTN
  short* pvT  = (short*)(base + al(SZ_vT));
  short* nvT  = (short*)(base + al(SZ_vT));
  short* pcT  = (short*)(base + al(SZ_cT));
  short* ncT  = (short*)(base + al(SZ_cT));
  float* scr8 = (float*)(base + al(SZ_p8));       // cemb [NCC][128] / part [4][NVV][128]
  short* cmPb = (short*)(base + al(SZ_cm));
  short* cmNb = (short*)(base + al(SZ_cm));
  short* cmTP = (short*)(base + al(SZ_cm));
  short* cmTN = (short*)(base + al(SZ_cm));
  const size_t needF = o;

  if (ws_size >= needF) {
    k_convT<<<dim3(NVV / 64, NCC / 64), 256, 0, stream>>>(cmat_pos, cmPb, cmTP, NCC, NVV);
    k_convT<<<dim3(NVV / 64, NCC / 64), 256, 0, stream>>>(cmat_neg, cmNb, cmTN, NCC, NVV);

    for (int it = 0; it < 4; ++it) {
      if (it == 0)
        k_mlp<0, 16><<<NVV / 16, 128, 0, stream>>>(vlabels, nullptr, nullptr, Wvp, Wvn, pvT, nvT, NVV, 0);
      else
        k_mlp<1, 16><<<NVV / 16, 128, 0, stream>>>(vlabels, out, nullptr, Wvp, Wvn, pvT, nvT, NVV, 0);

      // GEMM1 (no splitK, 256 blocks): cemb = relu(cmat@pv + cmatn@nv + Bv), f32
      k_gemm6<0, 0><<<NCC / 64, 256, 0, stream>>>(
          cmPb, cmNb, pvT, nvT, Bv, scr8, NCC, NVV, NVV, NVV);

      k_mlp<1, 16><<<NCC / 16, 128, 0, stream>>>(clabels, scr8, nullptr, Wcp, Wcn, pcT, ncT, NCC, 0);

      // GEMM2 (splitK=4, 256 blocks): partials = cmat^T @ pc (+neg)
      k_gemm6<1, 2><<<(NVV / 64) * 4, 256, 0, stream>>>(
          cmTP, cmTN, pcT, ncT, nullptr, scr8, NVV, NCC, NCC, NCC / 4);

      k_reduce_ln<4><<<NVV / 4, 256, 0, stream>>>(scr8, Bc, gam, bet, out);
    }
    return;
  }

  // ---- legacy layout: pvT nvT pcT ncT part(16MB) cemb(8MB) cmPb cmNb ----
  o = 0;
  pvT = (short*)(base + al(SZ_vT));
  nvT = (short*)(base + al(SZ_vT));
  pcT = (short*)(base + al(SZ_cT));
  ncT = (short*)(base + al(SZ_cT));
  float* part = (float*)(base + al(2 * SZ_p8));
  float* cemb = (float*)(base + al(SZ_p8));
  cmPb = (short*)(base + al(SZ_cm));
  cmNb = (short*)(base + al(SZ_cm));
  const size_t needN = o;
  const bool big = ws_size >= needN;

  if (big) {
    k_conv<<<4096, 256, 0, stream>>>(cmat_pos, cmPb, NCC * NVV / 8);
    k_conv<<<4096, 256, 0, stream>>>(cmat_neg, cmNb, NCC * NVV / 8);
  }

  for (int it = 0; it < 4; ++it) {
    if (it == 0)
      k_mlp<0, 16><<<NVV / 16, 128, 0, stream>>>(vlabels, nullptr, nullptr, Wvp, Wvn, pvT, nvT, NVV, 0);
    else
      k_mlp<1, 16><<<NVV / 16, 128, 0, stream>>>(vlabels, out, nullptr, Wvp, Wvn, pvT, nvT, NVV, 0);

    if (big) {
      k_gemm<short, false, 0><<<dim3(NCC / 32, 2, 1), 256, 0, stream>>>(
          cmPb, cmNb, pvT, nvT, Bv, cemb, NCC, NVV, NVV, NVV);
      k_mlp<1, 16><<<NCC / 16, 128, 0, stream>>>(clabels, cemb, nullptr, Wcp, Wcn, pcT, ncT, NCC, 0);
      k_gemm<short, true, 1><<<dim3(NVV / 32, 2, 4), 256, 0, stream>>>(
          cmPb, cmNb, pcT, ncT, nullptr, part, NVV, NVV, NCC, NVV);
      k_reduce_ln<4><<<NVV / 4, 256, 0, stream>>>(part, Bc, gam, bet, out);
    } else {
      k_gemm<float, false, 0><<<dim3(NCC / 32, 2, 1), 256, 0, stream>>>(
          cmat_pos, cmat_neg, pvT, nvT, Bv, cemb, NCC, NVV, NVV, NVV);
      k_mlp<1, 16><<<NCC / 16, 128, 0, stream>>>(clabels, cemb, nullptr, Wcp, Wcn, pcT, ncT, NCC, 0);
      k_gemm<float, true, 1><<<dim3(NVV / 32, 2, 4), 256, 0, stream>>>(
          cmat_pos, cmat_neg, pcT, ncT, nullptr, part, NVV, NVV, NCC, NVV);
      k_reduce_ln<4><<<NVV / 4, 256, 0, stream>>>(part, Bc, gam, bet, out);
    }
  }
}